// Round 1
// baseline (745.283 us; speedup 1.0000x reference)
//
#include <hip/hip_runtime.h>
#include <hip/hip_bf16.h>
#include <math.h>

// Problem constants
constexpr int LQ   = 64;     // queries per block
constexpr int KEYS = 65;     // 64 + block node
constexpr int NH   = 8;      // heads
constexpr int DH   = 64;     // head dim
constexpr int CC   = 512;    // channels
constexpr int TOK  = 65536;  // B*N
constexpr int NBLK = 1024;   // B*nb
constexpr int MEXT = TOK + NBLK;  // 66560 rows (tokens + block-node means)
constexpr int QKVLD = 3 * CC;     // 1536

using s16x8 = __attribute__((ext_vector_type(8))) short;
using f32x4 = __attribute__((ext_vector_type(4))) float;

__device__ __forceinline__ unsigned short f2bf(float f) {
  unsigned int u = __float_as_uint(f);
  u += 0x7fffu + ((u >> 16) & 1u);   // RNE; inputs are finite
  return (unsigned short)(u >> 16);
}

// ---------------- kernel 0: x fp32 -> bf16, append per-block mean rows ----
__global__ __launch_bounds__(256) void prep_x_kernel(const float* __restrict__ x,
                                                     unsigned short* __restrict__ xe) {
  const int blk = blockIdx.x;
  const int c = threadIdx.x * 2;
  const long base = (long)blk * LQ * CC;
  float s0 = 0.f, s1 = 0.f;
  for (int r = 0; r < LQ; ++r) {
    const float2 v = *(const float2*)(x + base + (long)r * CC + c);
    s0 += v.x; s1 += v.y;
    unsigned int p = (unsigned int)f2bf(v.x) | ((unsigned int)f2bf(v.y) << 16);
    *(unsigned int*)(xe + base + (long)r * CC + c) = p;
  }
  unsigned int pm = (unsigned int)f2bf(s0 * (1.f / 64.f)) |
                    ((unsigned int)f2bf(s1 * (1.f / 64.f)) << 16);
  *(unsigned int*)(xe + ((long)TOK + blk) * CC + c) = pm;
}

// ---------------- kernel 0b: weights fp32 -> bf16 ------------------------
__global__ __launch_bounds__(256) void prep_w_kernel(const float* __restrict__ qkvw,
                                                     const float* __restrict__ projw,
                                                     unsigned short* __restrict__ wq,
                                                     unsigned short* __restrict__ wp) {
  const int i = blockIdx.x * 256 + threadIdx.x;  // 262144 total float4s
  const float* src; unsigned short* dst; int j;
  if (i < 196608) { src = qkvw; dst = wq; j = i; }           // 1536*512/4
  else            { src = projw; dst = wp; j = i - 196608; } // 512*512/4
  const float4 v = *(const float4*)(src + (long)j * 4);
  unsigned int lo = (unsigned int)f2bf(v.x) | ((unsigned int)f2bf(v.y) << 16);
  unsigned int hi = (unsigned int)f2bf(v.z) | ((unsigned int)f2bf(v.w) << 16);
  uint2 o; o.x = lo; o.y = hi;
  *(uint2*)(dst + (long)j * 4) = o;
}

// ---------------- GEMM: C = A(MxK) * Bw(NxK)^T + bias, m97 structure -----
template <bool OUT_F32>
__global__ __launch_bounds__(256) void gemm_bt_kernel(
    const unsigned short* __restrict__ A,
    const unsigned short* __restrict__ Bw,
    const float* __restrict__ bias,
    void* __restrict__ Cv,
    int M, int Nn, int K, int tilesN) {
  __shared__ unsigned short lA[128 * 32];
  __shared__ unsigned short lB[128 * 32];
  const int bm = blockIdx.x / tilesN;
  const int bn = blockIdx.x % tilesN;
  const int t = threadIdx.x;
  const int w = t >> 6, lane = t & 63;
  const int l15 = lane & 15, l4 = lane >> 4;
  const int wr = w >> 1, wc = w & 1;
  const int srow = lane >> 2;          // row within 16-row chunk
  const int scol = (lane & 3) * 8;     // 8 bf16 = 16B per lane
  const long rowA0 = (long)bm * 128;
  const long rowB0 = (long)bn * 128;
  f32x4 acc[4][4] = {};
  for (int kk = 0; kk < K; kk += 32) {
#pragma unroll
    for (int i = 0; i < 2; ++i) {
      const int rc = w + 4 * i;  // 16-row chunk id, 0..7
      const unsigned short* gA = A + (rowA0 + rc * 16 + srow) * K + kk + scol;
      const unsigned short* gB = Bw + (rowB0 + rc * 16 + srow) * K + kk + scol;
      __builtin_amdgcn_global_load_lds((const __attribute__((address_space(1))) void*)gA,
                                       (__attribute__((address_space(3))) void*)(lA + rc * 16 * 32),
                                       16, 0, 0);
      __builtin_amdgcn_global_load_lds((const __attribute__((address_space(1))) void*)gB,
                                       (__attribute__((address_space(3))) void*)(lB + rc * 16 * 32),
                                       16, 0, 0);
    }
    __syncthreads();
    s16x8 af[4], bfr[4];
#pragma unroll
    for (int m = 0; m < 4; ++m)
      af[m] = *(const s16x8*)(lA + (wr * 64 + m * 16 + l15) * 32 + l4 * 8);
#pragma unroll
    for (int n = 0; n < 4; ++n)
      bfr[n] = *(const s16x8*)(lB + (wc * 64 + n * 16 + l15) * 32 + l4 * 8);
#pragma unroll
    for (int m = 0; m < 4; ++m)
#pragma unroll
      for (int n = 0; n < 4; ++n)
        acc[m][n] = __builtin_amdgcn_mfma_f32_16x16x32_bf16(af[m], bfr[n], acc[m][n], 0, 0, 0);
    __syncthreads();
  }
#pragma unroll
  for (int m = 0; m < 4; ++m) {
    const long row0 = rowA0 + wr * 64 + m * 16 + l4 * 4;
#pragma unroll
    for (int n = 0; n < 4; ++n) {
      const int col = (int)rowB0 + wc * 64 + n * 16 + l15;
      const float bv = bias[col];
#pragma unroll
      for (int r = 0; r < 4; ++r) {
        const float v = acc[m][n][r] + bv;
        if (OUT_F32) ((float*)Cv)[(row0 + r) * (long)Nn + col] = v;
        else ((unsigned short*)Cv)[(row0 + r) * (long)Nn + col] = f2bf(v);
      }
    }
  }
}

// ---------------- attention: 1 block per leaf-block, 1 wave per head -----
__global__ __launch_bounds__(512) void attn_kernel(
    const unsigned short* __restrict__ QKV,   // MEXT x 1536 bf16
    const int* __restrict__ amask,            // NBLK*64*65
    const float* __restrict__ edge,           // NBLK*64*65*4
    const float* __restrict__ egw,            // 8x4
    const float* __restrict__ egb,            // 8
    unsigned short* __restrict__ AO) {        // TOK x 512 bf16
  __shared__ unsigned short PS[NH][16 * 104]; // per-wave P transpose slice (stride 104 = 13*8)
  const int blk = blockIdx.x;
  const int t = threadIdx.x;
  const int h = t >> 6, lane = t & 63;
  const int l15 = lane & 15, l4 = lane >> 4;
  const long tokb = (long)blk * LQ;
  const long bnrow = (long)TOK + blk;
  const unsigned short* Qb = QKV + h * DH;
  const unsigned short* Kb = QKV + CC + h * DH;
  const unsigned short* Vb = QKV + 2 * CC + h * DH;
  const float eg0 = egw[h * 4 + 0], eg1 = egw[h * 4 + 1];
  const float eg2 = egw[h * 4 + 2], eg3 = egw[h * 4 + 3];
  const float egB = egb[h];
  unsigned short* myP = &PS[h][0];

  // V B-fragments vb[ks][dt]: lane holds V[key = ks*32 + l4*8 + j][d = dt*16 + l15]
  s16x8 vb[3][4];
#pragma unroll
  for (int dt = 0; dt < 4; ++dt) {
#pragma unroll
    for (int ks = 0; ks < 2; ++ks) {
      s16x8 f;
#pragma unroll
      for (int j = 0; j < 8; ++j) {
        const int key = ks * 32 + l4 * 8 + j;  // always < 64
        f[j] = (short)Vb[(tokb + key) * QKVLD + dt * 16 + l15];
      }
      vb[ks][dt] = f;
    }
    s16x8 f2 = {0, 0, 0, 0, 0, 0, 0, 0};      // keys 64..95: only key 64 real
    if (l4 == 0) f2[0] = (short)Vb[bnrow * QKVLD + dt * 16 + l15];
    vb[2][dt] = f2;
  }

  for (int i = 0; i < 4; ++i) {  // q-tiles of 16
    // Q A-fragments: lane holds Q[q = i*16 + l15][k = ks*32 + l4*8 + j]
    const s16x8 aq0 = *(const s16x8*)(Qb + (tokb + i * 16 + l15) * QKVLD + l4 * 8);
    const s16x8 aq1 = *(const s16x8*)(Qb + (tokb + i * 16 + l15) * QKVLD + 32 + l4 * 8);
    f32x4 sc[5];
#pragma unroll
    for (int jc = 0; jc < 5; ++jc) sc[jc] = {0.f, 0.f, 0.f, 0.f};
#pragma unroll
    for (int jc = 0; jc < 4; ++jc) {
      const s16x8 kf0 = *(const s16x8*)(Kb + (tokb + jc * 16 + l15) * QKVLD + l4 * 8);
      const s16x8 kf1 = *(const s16x8*)(Kb + (tokb + jc * 16 + l15) * QKVLD + 32 + l4 * 8);
      sc[jc] = __builtin_amdgcn_mfma_f32_16x16x32_bf16(aq0, kf0, sc[jc], 0, 0, 0);
      sc[jc] = __builtin_amdgcn_mfma_f32_16x16x32_bf16(aq1, kf1, sc[jc], 0, 0, 0);
    }
    {  // key tile 4: only key 64 (block node) real -> lane l15==0
      s16x8 kf0 = {0, 0, 0, 0, 0, 0, 0, 0};
      s16x8 kf1 = {0, 0, 0, 0, 0, 0, 0, 0};
      if (l15 == 0) {
        kf0 = *(const s16x8*)(Kb + bnrow * QKVLD + l4 * 8);
        kf1 = *(const s16x8*)(Kb + bnrow * QKVLD + 32 + l4 * 8);
      }
      sc[4] = __builtin_amdgcn_mfma_f32_16x16x32_bf16(aq0, kf0, sc[4], 0, 0, 0);
      sc[4] = __builtin_amdgcn_mfma_f32_16x16x32_bf16(aq1, kf1, sc[4], 0, 0, 0);
    }

    // scores + bias/mask + lew (D layout: q = i*16 + l4*4 + r, k = jc*16 + l15)
    float sv[5][4], lw[5][4];
#pragma unroll
    for (int jc = 0; jc < 5; ++jc) {
      const int k = jc * 16 + l15;
#pragma unroll
      for (int r = 0; r < 4; ++r) {
        const int qq = i * 16 + l4 * 4 + r;
        float val = sc[jc][r] * 0.125f;
        float lv = 0.f;
        if (k <= 64) {
          const long eidx = (tokb + qq) * KEYS + k;
          const int m = amask[eidx];
          float ex, ey, ez, ew;
          if (k == 64 || k == qq) { ex = 0.f; ey = 0.f; ez = 0.f; ew = 1.f; }
          else {
            const float4 e = *(const float4*)(edge + eidx * 4);
            ex = e.x; ey = e.y; ez = e.z; ew = e.w;
          }
          if (m != 0) {
            val += ew;
            lv = ex * eg0 + ey * eg1 + ez * eg2 + ew * eg3 + egB;
          } else val = -INFINITY;
        } else val = -INFINITY;
        sv[jc][r] = val; lw[jc][r] = lv;
      }
    }

    // row softmax over keys (reduce across the 16-lane group), then + lew -> P (bf16, LDS)
#pragma unroll
    for (int r = 0; r < 4; ++r) {
      float mx = sv[0][r];
#pragma unroll
      for (int jc = 1; jc < 5; ++jc) mx = fmaxf(mx, sv[jc][r]);
      mx = fmaxf(mx, __shfl_xor(mx, 1));
      mx = fmaxf(mx, __shfl_xor(mx, 2));
      mx = fmaxf(mx, __shfl_xor(mx, 4));
      mx = fmaxf(mx, __shfl_xor(mx, 8));
      float p[5], sum = 0.f;
#pragma unroll
      for (int jc = 0; jc < 5; ++jc) { p[jc] = __expf(sv[jc][r] - mx); sum += p[jc]; }
      sum += __shfl_xor(sum, 1);
      sum += __shfl_xor(sum, 2);
      sum += __shfl_xor(sum, 4);
      sum += __shfl_xor(sum, 8);
      const float inv = 1.f / sum;
      const int qrow = l4 * 4 + r;
#pragma unroll
      for (int jc = 0; jc < 5; ++jc)
        myP[qrow * 104 + jc * 16 + l15] = f2bf(p[jc] * inv + lw[jc][r]);
      myP[qrow * 104 + 80 + l15] = 0;  // zero pad keys 80..95
    }
    __syncthreads();  // LDS write->read safety (uniform across waves)

    // PV: A-fragments from LDS P slice, B-fragments = vb
    const s16x8 pa0 = *(const s16x8*)(myP + l15 * 104 + l4 * 8);
    const s16x8 pa1 = *(const s16x8*)(myP + l15 * 104 + 32 + l4 * 8);
    const s16x8 pa2 = *(const s16x8*)(myP + l15 * 104 + 64 + l4 * 8);
#pragma unroll
    for (int dt = 0; dt < 4; ++dt) {
      f32x4 oa = {0.f, 0.f, 0.f, 0.f};
      oa = __builtin_amdgcn_mfma_f32_16x16x32_bf16(pa0, vb[0][dt], oa, 0, 0, 0);
      oa = __builtin_amdgcn_mfma_f32_16x16x32_bf16(pa1, vb[1][dt], oa, 0, 0, 0);
      oa = __builtin_amdgcn_mfma_f32_16x16x32_bf16(pa2, vb[2][dt], oa, 0, 0, 0);
#pragma unroll
      for (int r = 0; r < 4; ++r)
        AO[(tokb + i * 16 + l4 * 4 + r) * (long)CC + h * DH + dt * 16 + l15] = f2bf(oa[r]);
    }
    __syncthreads();
  }
}

// ---------------- launcher ----------------------------------------------
extern "C" void kernel_launch(void* const* d_in, const int* in_sizes, int n_in,
                              void* d_out, int out_size, void* d_ws, size_t ws_size,
                              hipStream_t stream) {
  const float* x = (const float*)d_in[0];
  const int* amask = (const int*)d_in[1];
  const float* edge = (const float*)d_in[2];
  const float* qkvw = (const float*)d_in[3];
  const float* qkvb = (const float*)d_in[4];
  const float* projw = (const float*)d_in[5];
  const float* projb = (const float*)d_in[6];
  const float* egw = (const float*)d_in[7];
  const float* egb = (const float*)d_in[8];

  char* ws = (char*)d_ws;
  // layout: [xe: MEXT*512*2 = 68,157,440][qkv: MEXT*1536*2 = 204,472,320][wq][wp]
  unsigned short* xe  = (unsigned short*)ws;
  unsigned short* qkv = (unsigned short*)(ws + (size_t)68157440);
  unsigned short* wq  = (unsigned short*)(ws + (size_t)272629760);
  unsigned short* wp  = (unsigned short*)(ws + (size_t)274202624);
  unsigned short* ao  = xe;  // attn output reuses xe region (x dead after QKV GEMM)

  prep_x_kernel<<<dim3(NBLK), dim3(256), 0, stream>>>(x, xe);
  prep_w_kernel<<<dim3(1024), dim3(256), 0, stream>>>(qkvw, projw, wq, wp);
  gemm_bt_kernel<false><<<dim3(520 * 12), dim3(256), 0, stream>>>(
      xe, wq, qkvb, (void*)qkv, MEXT, 1536, 512, 12);
  attn_kernel<<<dim3(NBLK), dim3(512), 0, stream>>>(qkv, amask, edge, egw, egb, ao);
  gemm_bt_kernel<true><<<dim3(512 * 4), dim3(256), 0, stream>>>(
      ao, wp, projb, d_out, TOK, 512, 512, 4);
}

// Round 5
// 733.887 us; speedup vs baseline: 1.0155x; 1.0155x over previous
//
#include <hip/hip_runtime.h>
#include <hip/hip_bf16.h>
#include <math.h>

// Problem constants
constexpr int LQ   = 64;     // queries per block
constexpr int KEYS = 65;     // 64 + block node
constexpr int NH   = 8;      // heads
constexpr int DH   = 64;     // head dim
constexpr int CC   = 512;    // channels
constexpr int TOK  = 65536;  // B*N
constexpr int NBLK = 1024;   // B*nb
constexpr int MEXT = TOK + NBLK;  // 66560 rows (tokens + block-node means)

using s16x8 = __attribute__((ext_vector_type(8))) short;
using f32x4 = __attribute__((ext_vector_type(4))) float;

__device__ __forceinline__ unsigned short f2bf(float f) {
  unsigned int u = __float_as_uint(f);
  u += 0x7fffu + ((u >> 16) & 1u);   // RNE; inputs are finite
  return (unsigned short)(u >> 16);
}

// ---------------- kernel 0: x fp32 -> bf16, append per-block mean rows ----
__global__ __launch_bounds__(256) void prep_x_kernel(const float* __restrict__ x,
                                                     unsigned short* __restrict__ xe) {
  const int blk = blockIdx.x;
  const int c = threadIdx.x * 2;
  const long base = (long)blk * LQ * CC;
  float s0 = 0.f, s1 = 0.f;
  for (int r = 0; r < LQ; ++r) {
    const float2 v = *(const float2*)(x + base + (long)r * CC + c);
    s0 += v.x; s1 += v.y;
    unsigned int p = (unsigned int)f2bf(v.x) | ((unsigned int)f2bf(v.y) << 16);
    *(unsigned int*)(xe + base + (long)r * CC + c) = p;
  }
  unsigned int pm = (unsigned int)f2bf(s0 * (1.f / 64.f)) |
                    ((unsigned int)f2bf(s1 * (1.f / 64.f)) << 16);
  *(unsigned int*)(xe + ((long)TOK + blk) * CC + c) = pm;
}

// ---------------- kernel 0b: weights fp32 -> bf16 ------------------------
__global__ __launch_bounds__(256) void prep_w_kernel(const float* __restrict__ qkvw,
                                                     const float* __restrict__ projw,
                                                     unsigned short* __restrict__ wq,
                                                     unsigned short* __restrict__ wp) {
  const int i = blockIdx.x * 256 + threadIdx.x;  // 262144 total float4s
  const float* src; unsigned short* dst; int j;
  if (i < 196608) { src = qkvw; dst = wq; j = i; }           // 1536*512/4
  else            { src = projw; dst = wp; j = i - 196608; } // 512*512/4
  const float4 v = *(const float4*)(src + (long)j * 4);
  unsigned int lo = (unsigned int)f2bf(v.x) | ((unsigned int)f2bf(v.y) << 16);
  unsigned int hi = (unsigned int)f2bf(v.z) | ((unsigned int)f2bf(v.w) << 16);
  uint2 o; o.x = lo; o.y = hi;
  *(uint2*)(dst + (long)j * 4) = o;
}

// ---------------- GEMM: C = A(MxK) * Bw(NxK)^T + bias --------------------
// BK=64, XOR-swizzled LDS (pre-swizzled global source), XCD block swizzle.
// MODE 0: QKV output — cols <1024 go row-major bf16 (ld 1024) to out0 via
//         LDS-staged coalesced stores; cols >=1024 (V) go TRANSPOSED to
//         out1 as vt[d][row] with packed 8B stores.
// MODE 1: fp32 row-major (ld Nn) to out0.
template <int MODE>
__global__ __launch_bounds__(256) void gemm_bt_kernel(
    const unsigned short* __restrict__ A,
    const unsigned short* __restrict__ Bw,
    const float* __restrict__ bias,
    void* __restrict__ out0,
    unsigned short* __restrict__ out1,
    int M, int Nn, int K, int tilesN, int cpx) {
  __shared__ unsigned short sm[16384];  // 32KB: [A 128x64][B 128x64]; epilogue reuse 128x128
  const int bid = blockIdx.x;
  const int swz = (bid & 7) * cpx + (bid >> 3);   // XCD-aware (nwg%8==0)
  const int bm = swz / tilesN, bn = swz % tilesN;
  const int t = threadIdx.x;
  const int w = t >> 6, lane = t & 63;
  const int l15 = lane & 15, l4 = lane >> 4;
  const int wr = w >> 1, wc = w & 1;
  const int lrow = lane >> 3;                     // 0..7 (row&7 of staged row)
  const int lcol = ((lane & 7) ^ lrow) << 3;      // pre-swizzled source granule
  const int fsw = l15 & 7;
  const long rowA0 = (long)bm * 128;
  const int rowB0 = bn * 128;
  f32x4 acc[4][4] = {};
  for (int kk = 0; kk < K; kk += 64) {
#pragma unroll
    for (int c = 0; c < 4; ++c) {
      const int rr = c * 32 + w * 8 + lrow;
      const unsigned short* gA = A + (rowA0 + rr) * K + kk + lcol;
      const unsigned short* gB = Bw + (long)(rowB0 + rr) * K + kk + lcol;
      __builtin_amdgcn_global_load_lds((const __attribute__((address_space(1))) void*)gA,
                                       (__attribute__((address_space(3))) void*)(sm + c * 2048 + w * 512),
                                       16, 0, 0);
      __builtin_amdgcn_global_load_lds((const __attribute__((address_space(1))) void*)gB,
                                       (__attribute__((address_space(3))) void*)(sm + 8192 + c * 2048 + w * 512),
                                       16, 0, 0);
    }
    __syncthreads();
    s16x8 af[2][4], bf[2][4];
#pragma unroll
    for (int ks = 0; ks < 2; ++ks) {
#pragma unroll
      for (int m = 0; m < 4; ++m)
        af[ks][m] = *(const s16x8*)(sm + (wr * 64 + m * 16 + l15) * 64 + (((ks * 4 + l4) ^ fsw) << 3));
#pragma unroll
      for (int n = 0; n < 4; ++n)
        bf[ks][n] = *(const s16x8*)(sm + 8192 + (wc * 64 + n * 16 + l15) * 64 + (((ks * 4 + l4) ^ fsw) << 3));
    }
#pragma unroll
    for (int ks = 0; ks < 2; ++ks)
#pragma unroll
      for (int m = 0; m < 4; ++m)
#pragma unroll
        for (int n = 0; n < 4; ++n)
          acc[m][n] = __builtin_amdgcn_mfma_f32_16x16x32_bf16(af[ks][m], bf[ks][n], acc[m][n], 0, 0, 0);
    __syncthreads();
  }

  if (MODE == 1) {
    float* C = (float*)out0;
#pragma unroll
    for (int m = 0; m < 4; ++m) {
      const long row0 = rowA0 + wr * 64 + m * 16 + l4 * 4;
#pragma unroll
      for (int n = 0; n < 4; ++n) {
        const int col = rowB0 + wc * 64 + n * 16 + l15;
        const float bv = bias[col];
#pragma unroll
        for (int r = 0; r < 4; ++r)
          C[(row0 + r) * (long)Nn + col] = acc[m][n][r] + bv;
      }
    }
  } else if (rowB0 < 1024) {
    // Q,K -> LDS (granule-swizzled) -> coalesced 16B stores, ld=1024
#pragma unroll
    for (int m = 0; m < 4; ++m)
#pragma unroll
      for (int n = 0; n < 4; ++n) {
        const int col = wc * 64 + n * 16 + l15;
        const float bv = bias[rowB0 + col];
#pragma unroll
        for (int r = 0; r < 4; ++r) {
          const int row = wr * 64 + m * 16 + l4 * 4 + r;
          sm[row * 128 + (((col >> 3) ^ (row & 7)) << 3) + (col & 7)] = f2bf(acc[m][n][r] + bv);
        }
      }
    __syncthreads();
    unsigned short* qk = (unsigned short*)out0;
#pragma unroll
    for (int j = 0; j < 8; ++j) {
      const int idx = j * 256 + t;
      const int row = idx >> 4, g = idx & 15;
      const s16x8 v = *(const s16x8*)(sm + row * 128 + ((g ^ (row & 7)) << 3));
      *(s16x8*)(qk + (rowA0 + row) * 1024 + rowB0 + g * 8) = v;
    }
  } else {
    // V -> transposed vt[d][row], packed 8B stores (4 consecutive rows/lane)
#pragma unroll
    for (int m = 0; m < 4; ++m)
#pragma unroll
      for (int n = 0; n < 4; ++n) {
        const int colg = rowB0 + wc * 64 + n * 16 + l15;
        const float bv = bias[colg];
        uint2 o;
        o.x = (unsigned)f2bf(acc[m][n][0] + bv) | ((unsigned)f2bf(acc[m][n][1] + bv) << 16);
        o.y = (unsigned)f2bf(acc[m][n][2] + bv) | ((unsigned)f2bf(acc[m][n][3] + bv) << 16);
        *(uint2*)(out1 + (long)(colg - 1024) * MEXT + rowA0 + wr * 64 + m * 16 + l4 * 4) = o;
      }
  }
}

// ---------------- attention: 1 block per leaf-block, 1 wave per head -----
// No barriers: each wave's LDS slice is private. K/V fragments hoisted.
__global__ __launch_bounds__(512) void attn_kernel(
    const unsigned short* __restrict__ QK,    // MEXT x 1024 bf16 (q | k)
    const unsigned short* __restrict__ VT,    // 512 x MEXT bf16 (transposed v)
    const int* __restrict__ amask,            // NBLK*64*65
    const float* __restrict__ edge,           // NBLK*64*65*4
    const float* __restrict__ egw,            // 8x4
    const float* __restrict__ egb,            // 8
    unsigned short* __restrict__ AO) {        // TOK x 512 bf16
  __shared__ unsigned short PS[NH][16 * 104]; // per-wave P/O slice
  const int blk = blockIdx.x;
  const int t = threadIdx.x;
  const int h = t >> 6, lane = t & 63;
  const int l15 = lane & 15, l4 = lane >> 4;
  const long tokb = (long)blk * LQ;
  const long bnrow = (long)TOK + blk;
  const unsigned short* Qb = QK + h * DH;
  const unsigned short* Kb = QK + CC + h * DH;
  const unsigned short* Vt = VT + (long)h * DH * MEXT;
  const float eg0 = egw[h * 4 + 0], eg1 = egw[h * 4 + 1];
  const float eg2 = egw[h * 4 + 2], eg3 = egw[h * 4 + 3];
  const float egB = egb[h];
  unsigned short* myP = &PS[h][0];

  // K fragments (hoisted): kf[jc][ks] lane holds K[k=jc*16+l15][d=ks*32+l4*8+j]
  s16x8 kf[4][2];
#pragma unroll
  for (int jc = 0; jc < 4; ++jc) {
    kf[jc][0] = *(const s16x8*)(Kb + (tokb + jc * 16 + l15) * 1024 + l4 * 8);
    kf[jc][1] = *(const s16x8*)(Kb + (tokb + jc * 16 + l15) * 1024 + 32 + l4 * 8);
  }
  s16x8 kf4[2] = {{0,0,0,0,0,0,0,0},{0,0,0,0,0,0,0,0}};
  if (l15 == 0) {
    kf4[0] = *(const s16x8*)(Kb + bnrow * 1024 + l4 * 8);
    kf4[1] = *(const s16x8*)(Kb + bnrow * 1024 + 32 + l4 * 8);
  }

  // V B-fragments from vt: vb[ks][dt] lane holds V[key=ks*32+l4*8+j][d=dt*16+l15]
  s16x8 vb[3][4];
#pragma unroll
  for (int dt = 0; dt < 4; ++dt) {
    const unsigned short* vrow = Vt + (long)(dt * 16 + l15) * MEXT;
    vb[0][dt] = *(const s16x8*)(vrow + tokb + l4 * 8);
    vb[1][dt] = *(const s16x8*)(vrow + tokb + 32 + l4 * 8);
    s16x8 f2 = {0, 0, 0, 0, 0, 0, 0, 0};
    if (l4 == 0) f2[0] = (short)vrow[bnrow];   // key 64 (block node)
    vb[2][dt] = f2;
  }

  for (int i = 0; i < 4; ++i) {  // q-tiles of 16
    const s16x8 aq0 = *(const s16x8*)(Qb + (tokb + i * 16 + l15) * 1024 + l4 * 8);
    const s16x8 aq1 = *(const s16x8*)(Qb + (tokb + i * 16 + l15) * 1024 + 32 + l4 * 8);
    f32x4 sc[5];
#pragma unroll
    for (int jc = 0; jc < 5; ++jc) sc[jc] = {0.f, 0.f, 0.f, 0.f};
#pragma unroll
    for (int jc = 0; jc < 4; ++jc) {
      sc[jc] = __builtin_amdgcn_mfma_f32_16x16x32_bf16(aq0, kf[jc][0], sc[jc], 0, 0, 0);
      sc[jc] = __builtin_amdgcn_mfma_f32_16x16x32_bf16(aq1, kf[jc][1], sc[jc], 0, 0, 0);
    }
    sc[4] = __builtin_amdgcn_mfma_f32_16x16x32_bf16(aq0, kf4[0], sc[4], 0, 0, 0);
    sc[4] = __builtin_amdgcn_mfma_f32_16x16x32_bf16(aq1, kf4[1], sc[4], 0, 0, 0);

    // per accumulator row: bias/mask + softmax + lew -> P (bf16, LDS)
#pragma unroll
    for (int r = 0; r < 4; ++r) {
      const int qq = i * 16 + l4 * 4 + r;
      float sv[5], lw[5];
#pragma unroll
      for (int jc = 0; jc < 5; ++jc) {
        const int k = jc * 16 + l15;
        float val = sc[jc][r] * 0.125f;
        float lv = 0.f;
        if (k <= 64) {
          const long eidx = (tokb + qq) * KEYS + k;
          const int m = amask[eidx];
          float ex, ey, ez, ew;
          if (k == 64 || k == qq) { ex = 0.f; ey = 0.f; ez = 0.f; ew = 1.f; }
          else {
            const float4 e = *(const float4*)(edge + eidx * 4);
            ex = e.x; ey = e.y; ez = e.z; ew = e.w;
          }
          if (m != 0) {
            val += ew;
            lv = ex * eg0 + ey * eg1 + ez * eg2 + ew * eg3 + egB;
          } else val = -INFINITY;
        } else val = -INFINITY;
        sv[jc] = val; lw[jc] = lv;
      }
      float mx = fmaxf(fmaxf(fmaxf(sv[0], sv[1]), fmaxf(sv[2], sv[3])), sv[4]);
      mx = fmaxf(mx, __shfl_xor(mx, 1));
      mx = fmaxf(mx, __shfl_xor(mx, 2));
      mx = fmaxf(mx, __shfl_xor(mx, 4));
      mx = fmaxf(mx, __shfl_xor(mx, 8));
      float p[5], sum = 0.f;
#pragma unroll
      for (int jc = 0; jc < 5; ++jc) { p[jc] = __expf(sv[jc] - mx); sum += p[jc]; }
      sum += __shfl_xor(sum, 1);
      sum += __shfl_xor(sum, 2);
      sum += __shfl_xor(sum, 4);
      sum += __shfl_xor(sum, 8);
      const float inv = 1.f / sum;
      const int qrow = l4 * 4 + r;
#pragma unroll
      for (int jc = 0; jc < 5; ++jc)
        myP[qrow * 104 + jc * 16 + l15] = f2bf(p[jc] * inv + lw[jc]);
      myP[qrow * 104 + 80 + l15] = 0;  // zero pad keys 80..95
    }

    // PV: A-fragments from LDS P slice, B-fragments = vb
    const s16x8 pa0 = *(const s16x8*)(myP + l15 * 104 + l4 * 8);
    const s16x8 pa1 = *(const s16x8*)(myP + l15 * 104 + 32 + l4 * 8);
    const s16x8 pa2 = *(const s16x8*)(myP + l15 * 104 + 64 + l4 * 8);
#pragma unroll
    for (int dt = 0; dt < 4; ++dt) {
      f32x4 oa = {0.f, 0.f, 0.f, 0.f};
      oa = __builtin_amdgcn_mfma_f32_16x16x32_bf16(pa0, vb[0][dt], oa, 0, 0, 0);
      oa = __builtin_amdgcn_mfma_f32_16x16x32_bf16(pa1, vb[1][dt], oa, 0, 0, 0);
      oa = __builtin_amdgcn_mfma_f32_16x16x32_bf16(pa2, vb[2][dt], oa, 0, 0, 0);
      // stage O rows into the (now dead) P slice cols 0..63
#pragma unroll
      for (int r = 0; r < 4; ++r)
        myP[(l4 * 4 + r) * 104 + dt * 16 + l15] = f2bf(oa[r]);
    }
    // coalesced O store: 16B per lane, two granules
    {
      const int row16 = lane >> 2, gsel = lane & 3;
      const s16x8 o0 = *(const s16x8*)(myP + row16 * 104 + gsel * 8);
      const s16x8 o1 = *(const s16x8*)(myP + row16 * 104 + (gsel + 4) * 8);
      unsigned short* dst = AO + (tokb + i * 16 + row16) * CC + h * DH;
      *(s16x8*)(dst + gsel * 8) = o0;
      *(s16x8*)(dst + (gsel + 4) * 8) = o1;
    }
  }
}

// ---------------- launcher ----------------------------------------------
extern "C" void kernel_launch(void* const* d_in, const int* in_sizes, int n_in,
                              void* d_out, int out_size, void* d_ws, size_t ws_size,
                              hipStream_t stream) {
  const float* x = (const float*)d_in[0];
  const int* amask = (const int*)d_in[1];
  const float* edge = (const float*)d_in[2];
  const float* qkvw = (const float*)d_in[3];
  const float* qkvb = (const float*)d_in[4];
  const float* projw = (const float*)d_in[5];
  const float* projb = (const float*)d_in[6];
  const float* egw = (const float*)d_in[7];
  const float* egb = (const float*)d_in[8];

  char* ws = (char*)d_ws;
  // [xe: 68,157,440][qk: 136,314,880][vt: 68,157,440][wq: 1,572,864][wp: 524,288]
  unsigned short* xe = (unsigned short*)ws;
  unsigned short* qk = (unsigned short*)(ws + (size_t)68157440);
  unsigned short* vt = (unsigned short*)(ws + (size_t)204472320);
  unsigned short* wq = (unsigned short*)(ws + (size_t)272629760);
  unsigned short* wp = (unsigned short*)(ws + (size_t)274202624);
  unsigned short* ao = xe;  // attn output reuses xe (dead after QKV GEMM)

  prep_x_kernel<<<dim3(NBLK), dim3(256), 0, stream>>>(x, xe);
  prep_w_kernel<<<dim3(1024), dim3(256), 0, stream>>>(qkvw, projw, wq, wp);
  gemm_bt_kernel<0><<<dim3(520 * 12), dim3(256), 0, stream>>>(
      xe, wq, qkvb, (void*)qk, vt, MEXT, 1536, 512, 12, 780);
  attn_kernel<<<dim3(NBLK), dim3(512), 0, stream>>>(qk, vt, amask, edge, egw, egb, ao);
  gemm_bt_kernel<1><<<dim3(512 * 4), dim3(256), 0, stream>>>(
      ao, wp, projb, d_out, nullptr, TOK, 512, 512, 4, 256);
}